// Round 2
// 700.409 us; speedup vs baseline: 1.0247x; 1.0247x over previous
//
#include <hip/hip_runtime.h>

typedef unsigned short u16;
typedef unsigned int   u32;
typedef unsigned long long u64;

typedef __attribute__((ext_vector_type(8))) short  short8;
typedef __attribute__((ext_vector_type(4))) float  floatx4;

__device__ __forceinline__ u16 f2bf(float f) {
    u32 u = __float_as_uint(f);
    u32 r = (u + 0x7FFFu + ((u >> 16) & 1u)) >> 16;   // RNE
    return (u16)r;
}
__device__ __forceinline__ float bfu2f(u16 u) {
    union { u32 i; float f; } v; v.i = ((u32)u) << 16; return v.f;
}

constexpr int N     = 768;
constexpr int TOPK  = 30;
// output element offsets (f32 elements, concatenated tuple)
constexpr long OFF_ANG = 393216;                       // 2*768*256
constexpr long OFF_DST = 6291456;                      // + 2*768*30*128
constexpr long OFF_RP  = 12189696;                     // + 2*768*30*128

// deterministic, contraction-free f32 distance (match np rounding)
__device__ __forceinline__ float dist_f32(float dx, float dy, float dz) {
    float s = __fadd_rn(__fadd_rn(__fmul_rn(dx, dx), __fmul_rn(dy, dy)), __fmul_rn(dz, dz));
    return __fsqrt_rn(s);
}

// ---------------------------------------------------------------------------
// K1 (merged): blocks [0,384): per-row top-30 selection + geometric features
//              (one wave per row; 1536 rows).
//              blocks [384,1536): relpos writer. 1152 blocks x 32768 floatx4.
//              W_rp+b_rp summed into LDS once per block; hot loop is
//              index-math -> ds_read_b128 -> coalesced 16B store (no global
//              reads). Blocks never straddle the batch boundary
//              (589824 rows = 576 * 1024).
// ---------------------------------------------------------------------------
__global__ __launch_bounds__(256) void topk_relpos_kernel(
    const float* __restrict__ frames, const int* __restrict__ resi,
    const float* __restrict__ smask, float* __restrict__ feat,
    const float* __restrict__ W_rp, const float* __restrict__ b_rp,
    float* __restrict__ out)
{
    // union'd LDS: topk needs 15360 B, relpos needs 36352 B
    __shared__ __align__(16) char smem_raw[65 * 128 * 4 + N * 4];
    int tid = threadIdx.x;

    if (blockIdx.x < 384) {
        // ------------------------- top-k + features -------------------------
        float* s_t = (float*)smem_raw;         // N*3 f32
        float* s_m = s_t + N * 3;              // N f32
        int*   s_r = (int*)(s_m + N);          // N i32

        int r0  = blockIdx.x * 4;
        int b   = r0 / N;                      // blocks never straddle batches (4 | 768)
        for (int j = tid; j < N; j += 256) {
            s_r[j] = resi[b * N + j];
            s_m[j] = smask[b * N + j];
            long fb = (long)(b * N + j) * 16;
            s_t[j * 3 + 0] = frames[fb + 0 * 4 + 3];
            s_t[j * 3 + 1] = frames[fb + 1 * 4 + 3];
            s_t[j * 3 + 2] = frames[fb + 2 * 4 + 3];
        }
        __syncthreads();

        int wave = tid >> 6, lane = tid & 63;
        int r = r0 + wave;
        int i = r - b * N;
        float ti0 = s_t[i * 3], ti1 = s_t[i * 3 + 1], ti2 = s_t[i * 3 + 2];
        float mi = s_m[i];
        int   ri = s_r[i];

        // keys: sortable(d4topk) in high 32, index j in low 32 (ties -> lower j)
        u64 keys[12];
#pragma unroll
        for (int c = 0; c < 12; c++) {
            int j = lane + 64 * c;
            float dx = __fadd_rn(s_t[j * 3 + 0], -ti0);
            float dy = __fadd_rn(s_t[j * 3 + 1], -ti1);
            float dz = __fadd_rn(s_t[j * 3 + 2], -ti2);
            float dist = dist_f32(dx, dy, dz);
            int rd = s_r[j] - ri;
            bool conn = (rd == 1) || (rd == -1);
            bool bad  = (j == i) || (mi == 0.f) || (s_m[j] == 0.f);
            float d4 = conn ? -1e10f : (bad ? 1e10f : dist);
            u32 u = __float_as_uint(d4);
            u32 su = (u >> 31) ? ~u : (u | 0x80000000u);
            keys[c] = ((u64)su << 32) | (u32)j;
        }

        int my_j = 0;
        for (int k = 0; k < TOPK; k++) {
            u64 m = keys[0];
#pragma unroll
            for (int c = 1; c < 12; c++) m = m < keys[c] ? m : keys[c];
#pragma unroll
            for (int off = 32; off >= 1; off >>= 1) {
                u32 lo = (u32)m, hi = (u32)(m >> 32);
                u32 lo2 = __shfl_xor(lo, off);
                u32 hi2 = __shfl_xor(hi, off);
                u64 o = ((u64)hi2 << 32) | lo2;
                m = m < o ? m : o;
            }
            // invalidate winner by value (keys unique: j embedded)
#pragma unroll
            for (int c = 0; c < 12; c++) keys[c] = (keys[c] == m) ? ~0ull : keys[c];
            if (lane == k) my_j = (int)(m & 0xffffffffu);
        }

        if (lane < TOPK) {
            int j = my_j;
            float dx = __fadd_rn(s_t[j * 3 + 0], -ti0);
            float dy = __fadd_rn(s_t[j * 3 + 1], -ti1);
            float dz = __fadd_rn(s_t[j * 3 + 2], -ti2);
            float dist = dist_f32(dx, dy, dz);
            long fb = (long)(b * N + i) * 16;
            float R00 = frames[fb + 0], R01 = frames[fb + 1], R02 = frames[fb + 2];
            float R10 = frames[fb + 4], R11 = frames[fb + 5], R12 = frames[fb + 6];
            float R20 = frames[fb + 8], R21 = frames[fb + 9], R22 = frames[fb + 10];
            // t_rel[y] = sum_x R[x][y] * rel[x]
            float t0 = R00 * dx + R10 * dy + R20 * dz;
            float t1 = R01 * dx + R11 * dy + R21 * dz;
            float t2 = R02 * dx + R12 * dy + R22 * dz;
            float a0 = dist > 0.f ? t0 / dist : 0.f;
            float a1 = dist > 0.f ? t1 / dist : 0.f;
            float a2 = dist > 0.f ? t2 / dist : 0.f;
            int rd = s_r[j] - ri;
            float conn = ((rd == 1) || (rd == -1)) ? 1.f : 0.f;
            float eye  = (j == i) ? 1.f : 0.f;
            long base = ((long)r * TOPK + lane) * 8;
            feat[base + 0] = eye; feat[base + 1] = conn;
            feat[base + 2] = a0;  feat[base + 3] = a1; feat[base + 4] = a2;
            feat[base + 5] = eye; feat[base + 6] = conn; feat[base + 7] = dist;
        }
    } else {
        // ----------------------------- relpos -------------------------------
        float* T   = (float*)smem_raw;         // 65*128 f32: W_rp + b_rp
        int*   s_r = (int*)(T + 65 * 128);     // N i32

        int blk = blockIdx.x - 384;            // [0,1152)
        int b   = blk >= 576;                  // batch (1024 rows/blk, 576*1024 = N*N)

        for (int e = tid; e < 65 * 128; e += 256) T[e] = W_rp[e] + b_rp[e & 127];
        for (int j = tid; j < N; j += 256) s_r[j] = resi[b * N + j];
        __syncthreads();

        long vbase   = (long)blk << 15;            // 32768 floatx4 per block
        int  rowbase = (blk - b * 576) << 10;      // local row within batch
        floatx4* dst = (floatx4*)(out + OFF_RP) + vbase;

#pragma unroll 4
        for (int it = 0; it < 128; ++it) {
            int lv  = (it << 8) + tid;             // [0,32768)
            unsigned lrow = (unsigned)(rowbase + (lv >> 5));
            int seg = lv & 31;                     // 32 floatx4 per 128-f32 row
            unsigned i = lrow / 768u;
            unsigned j = lrow - i * 768u;
            int d = s_r[i] - s_r[j];
            d = d < -32 ? -32 : (d > 32 ? 32 : d);
            dst[lv] = ((const floatx4*)(T + (unsigned)(d + 32) * 128))[seg];
        }
    }
}

// ---------------------------------------------------------------------------
// K2 (fused): blocks [0,720) embed-angle; [720,1440) embed-dist; [1440,1824) s.
// embed: out = gelu(feat@W1+b1) @ W2 + b2 via bf16 MFMA, A and B hi/lo split.
// ---------------------------------------------------------------------------
template<int NF, int FOFF>
__device__ __forceinline__ void embed_body(
    int blk, const float* __restrict__ feat,
    const float* __restrict__ W1, const float* __restrict__ b1,
    const float* __restrict__ W2, const float* __restrict__ b2,
    float* __restrict__ out,
    u16* s_w2h, u16* s_w2l, float* s_w1, float* s_b1, float* s_b2)
{
    int tid = threadIdx.x;
    for (int e = tid; e < 128 * 128; e += 256) {
        int kk = e >> 7, nn = e & 127;
        float w  = W2[e];
        u16 hi = f2bf(w);
        float lo = __fadd_rn(w, -bfu2f(hi));
        s_w2h[nn * 136 + kk] = hi;
        s_w2l[nn * 136 + kk] = f2bf(lo);
    }
    for (int e = tid; e < NF * 128; e += 256) s_w1[e] = W1[e];
    if (tid < 128) { s_b1[tid] = b1[tid]; s_b2[tid] = b2[tid]; }
    __syncthreads();

    int wave = tid >> 6, lane = tid & 63;
    int m = lane & 15, q = lane >> 4;
    int row0 = blk * 64 + wave * 16;
    int row  = row0 + m;

    float f[NF];
#pragma unroll
    for (int t = 0; t < NF; t++) f[t] = feat[(long)row * 8 + FOFF + t];

    floatx4 acc[8];
#pragma unroll
    for (int nt = 0; nt < 8; nt++) acc[nt] = (floatx4){0.f, 0.f, 0.f, 0.f};

#pragma unroll
    for (int s = 0; s < 4; s++) {
        short8 ahi, alo;
#pragma unroll
        for (int jj = 0; jj < 8; jj++) {
            int kk = 32 * s + 8 * q + jj;
            float h = s_b1[kk];
#pragma unroll
            for (int t = 0; t < NF; t++) h += f[t] * s_w1[t * 128 + kk];
            // gelu (tanh approx = jax.nn.gelu default), overflow-safe
            float u  = 0.7978845608028654f * (h + 0.044715f * h * h * h);
            float e2 = __expf(-2.f * fabsf(u));
            float th = (1.f - e2) / (1.f + e2);
            th = u < 0.f ? -th : th;
            float g = 0.5f * h * (1.f + th);
            u16 ghi = f2bf(g);
            float glo = __fadd_rn(g, -bfu2f(ghi));
            ahi[jj] = (short)ghi;
            alo[jj] = (short)f2bf(glo);
        }
#pragma unroll
        for (int nt = 0; nt < 8; nt++) {
            int boff = (nt * 16 + m) * 136 + 32 * s + 8 * q;
            short8 bh = *(const short8*)&s_w2h[boff];
            short8 bl = *(const short8*)&s_w2l[boff];
            acc[nt] = __builtin_amdgcn_mfma_f32_16x16x32_bf16(ahi, bh, acc[nt], 0, 0, 0);
            acc[nt] = __builtin_amdgcn_mfma_f32_16x16x32_bf16(alo, bh, acc[nt], 0, 0, 0);
            acc[nt] = __builtin_amdgcn_mfma_f32_16x16x32_bf16(ahi, bl, acc[nt], 0, 0, 0);
        }
    }

#pragma unroll
    for (int nt = 0; nt < 8; nt++) {
#pragma unroll
        for (int rg = 0; rg < 4; rg++) {
            int rr = row0 + q * 4 + rg;      // C/D: row = quad*4 + reg
            int cc = nt * 16 + m;            // C/D: col = lane&15
            out[(long)rr * 128 + cc] = acc[nt][rg] + s_b2[cc];
        }
    }
}

__global__ __launch_bounds__(256) void fused_embed_s_kernel(
    const float* __restrict__ feat,
    const float* __restrict__ Wa1, const float* __restrict__ ba1,
    const float* __restrict__ Wa2, const float* __restrict__ ba2,
    const float* __restrict__ Wd1, const float* __restrict__ bd1,
    const float* __restrict__ Wd2, const float* __restrict__ bd2,
    const float* __restrict__ W_tf, const float* __restrict__ b_tf,
    float* __restrict__ out)
{
    __shared__ __align__(16) u16 s_w2h[128 * 136];
    __shared__ __align__(16) u16 s_w2l[128 * 136];
    __shared__ float s_w1[5 * 128];
    __shared__ float s_b1[128];
    __shared__ float s_b2[128];
    unsigned bx = blockIdx.x;
    if (bx < 720) {
        embed_body<5, 0>(bx, feat, Wa1, ba1, Wa2, ba2, out + OFF_ANG,
                         s_w2h, s_w2l, s_w1, s_b1, s_b2);
    } else if (bx < 1440) {
        embed_body<3, 5>(bx - 720, feat, Wd1, bd1, Wd2, bd2, out + OFF_DST,
                         s_w2h, s_w2l, s_w1, s_b1, s_b2);
    } else {
        int gid = (bx - 1440) * 256 + threadIdx.x;   // floatx4 idx over 2*768*256
        int c0  = (gid * 4) & 255;
        floatx4 o;
        o.x = W_tf[c0 + 0] + b_tf[c0 + 0];
        o.y = W_tf[c0 + 1] + b_tf[c0 + 1];
        o.z = W_tf[c0 + 2] + b_tf[c0 + 2];
        o.w = W_tf[c0 + 3] + b_tf[c0 + 3];
        *((floatx4*)out + gid) = o;
    }
}

extern "C" void kernel_launch(void* const* d_in, const int* in_sizes, int n_in,
                              void* d_out, int out_size, void* d_ws, size_t ws_size,
                              hipStream_t stream) {
    const int*   resi   = (const int*)d_in[1];
    const float* frames = (const float*)d_in[2];
    const float* smask  = (const float*)d_in[3];
    const float* W_tf   = (const float*)d_in[4];
    const float* b_tf   = (const float*)d_in[5];
    const float* Wa1    = (const float*)d_in[6];
    const float* ba1    = (const float*)d_in[7];
    const float* Wa2    = (const float*)d_in[8];
    const float* ba2    = (const float*)d_in[9];
    const float* Wd1    = (const float*)d_in[10];
    const float* bd1    = (const float*)d_in[11];
    const float* Wd2    = (const float*)d_in[12];
    const float* bd2    = (const float*)d_in[13];
    const float* W_rp   = (const float*)d_in[14];
    const float* b_rp   = (const float*)d_in[15];
    float* out  = (float*)d_out;
    float* feat = (float*)d_ws;    // 46080 * 8 fp32 = 1.47 MB

    hipLaunchKernelGGL(topk_relpos_kernel, dim3(1536), dim3(256), 0, stream,
                       frames, resi, smask, feat, W_rp, b_rp, out);
    hipLaunchKernelGGL(fused_embed_s_kernel, dim3(1824), dim3(256), 0, stream,
                       feat, Wa1, ba1, Wa2, ba2, Wd1, bd1, Wd2, bd2,
                       W_tf, b_tf, out);
}